// Round 6
// baseline (284.399 us; speedup 1.0000x reference)
//
#include <hip/hip_runtime.h>

#define BB 4
#define NN 16384
#define SS 4096
#define CIN 256
#define COUT 256

#define SC 8                  // s-chunks for knn
#define SCS (SS / SC)         // 512 points per chunk
#define NPT 4                 // queries per thread in knn
#define KNNB ((NN / (256 * NPT)) * SC * BB)   // 16*8*4 = 512 knn blocks
#define GEMMB ((COUT / 64) * (SS / 64) * BB)  // 4*64*4 = 1024 gemm blocks

// ---------------------------------------------------------------------------
// Fused kernel: blocks [0, KNNB) = partial 3-NN; [KNNB, KNNB+GEMMB) = GEMM.
// __launch_bounds__(256,4): min 4 waves/EU -> 128-VGPR budget, stops the
// RA's AGPR-shuttle (round-3/4 showed VGPR_Count 20/32 with ~2.4x inst bloat).
// ---------------------------------------------------------------------------
__global__ __launch_bounds__(256, 4) void k_fused(const float* __restrict__ xyz1,
                                                  const float* __restrict__ xyz2,
                                                  const float* __restrict__ P,
                                                  const float* __restrict__ W,
                                                  const float* __restrict__ bias,
                                                  float* __restrict__ G,
                                                  float* __restrict__ pd,
                                                  int* __restrict__ pi) {
    __shared__ float4 smv[528];   // 8448 B, aliased by both paths
    int bid = blockIdx.x;
    int t   = threadIdx.x;

    if (bid < KNNB) {
        // ---------------- knn path ----------------
        int nb = bid & 15;            // 16 n-blocks (1024 queries each)
        int ch = (bid >> 4) & 7;
        int b  = bid >> 7;
        int s0 = ch * SCS;

        const float* x2 = xyz2 + (size_t)b * 3 * SS;
        for (int i = t; i < SCS; i += 256) {
            float px = x2[s0 + i];
            float py = x2[SS + s0 + i];
            float pz = x2[2 * SS + s0 + i];
            smv[i] = make_float4(px, py, pz, fmaf(px, px, fmaf(py, py, pz * pz)));
        }
        __syncthreads();

        int n0 = nb * (256 * NPT) + t;
        const float* xb = xyz1 + (size_t)b * 3 * NN;

        float xm2[NPT], ym2[NPT], zm2[NPT], n1[NPT];
        float d0[NPT], d1[NPT], d2[NPT];
        int   i0[NPT], i1[NPT], i2[NPT];
#pragma unroll
        for (int k = 0; k < NPT; ++k) {
            int n = n0 + 256 * k;
            float qx = xb[n], qy = xb[NN + n], qz = xb[2 * NN + n];
            n1[k]  = fmaf(qx, qx, fmaf(qy, qy, qz * qz));
            xm2[k] = -2.0f * qx; ym2[k] = -2.0f * qy; zm2[k] = -2.0f * qz;
            d0[k] = d1[k] = d2[k] = 3.4e38f;
            i0[k] = i1[k] = i2[k] = 0;
        }

#pragma unroll 4
        for (int s = 0; s < SCS; ++s) {
            float4 p = smv[s];
            int gs = s0 + s;
#pragma unroll
            for (int k = 0; k < NPT; ++k) {
                // ranking key e = -2*dot + |p2|^2 (query-const |p1|^2 added at store)
                float e = fmaf(p.x, xm2[k], fmaf(p.y, ym2[k], fmaf(p.z, zm2[k], p.w)));
                bool c0 = e < d0[k];
                bool c1 = e < d1[k];
                bool c2 = e < d2[k];
                // distances: min/med3 network (== the cndmask chain, case-checked)
                d2[k] = __builtin_amdgcn_fmed3f(d1[k], e, d2[k]);
                d1[k] = __builtin_amdgcn_fmed3f(d0[k], e, d1[k]);
                d0[k] = fminf(d0[k], e);
                // indices: 5 cndmask
                i2[k] = c1 ? i1[k] : (c2 ? gs : i2[k]);
                i1[k] = c0 ? i0[k] : (c1 ? gs : i1[k]);
                i0[k] = c0 ? gs : i0[k];
            }
        }

#pragma unroll
        for (int k = 0; k < NPT; ++k) {
            int n = n0 + 256 * k;
            size_t base = ((size_t)(ch * BB + b) * NN + n) * 3;
            pd[base + 0] = d0[k] + n1[k];
            pd[base + 1] = d1[k] + n1[k];
            pd[base + 2] = d2[k] + n1[k];
            pi[base + 0] = i0[k];
            pi[base + 1] = i1[k];
            pi[base + 2] = i2[k];
        }
    } else {
        // ---------------- gemm path ----------------
        int g  = bid - KNNB;
        int o0 = (g & 3) * 64;
        int s0 = ((g >> 2) & 63) * 64;
        int b  = g >> 8;
        float* sP = (float*)smv;           // 16x64 floats
        float* sW = (float*)smv + 1024;    // 16x68 floats (padded)
        int i = t & 15;
        int j = t >> 4;

        float acc[4][4];
#pragma unroll
        for (int p = 0; p < 4; ++p)
#pragma unroll
            for (int q = 0; q < 4; ++q) acc[p][q] = 0.f;

        const float* Pb = P + (size_t)b * CIN * SS;

        for (int c0 = 0; c0 < CIN; c0 += 16) {
            __syncthreads();
            {
                int col = t & 63;
                int r0r = t >> 6;
#pragma unroll
                for (int r = 0; r < 4; ++r) {
                    int row = r0r + r * 4;
                    sP[row * 64 + col] = Pb[(size_t)(c0 + row) * SS + s0 + col];
                }
            }
            {
                int cc = t & 15;
                int obase = t >> 4;
#pragma unroll
                for (int r = 0; r < 4; ++r) {
                    int oo = obase + 16 * r;
                    sW[cc * 68 + oo] = W[(size_t)(o0 + oo) * CIN + c0 + cc];
                }
            }
            __syncthreads();

#pragma unroll
            for (int cc = 0; cc < 16; ++cc) {
                float4 a  = *(const float4*)&sP[cc * 64 + i * 4];
                float4 bv = *(const float4*)&sW[cc * 68 + j * 4];
                float av[4] = {a.x, a.y, a.z, a.w};
                float bw[4] = {bv.x, bv.y, bv.z, bv.w};
#pragma unroll
                for (int p = 0; p < 4; ++p)
#pragma unroll
                    for (int q = 0; q < 4; ++q)
                        acc[p][q] = fmaf(av[p], bw[q], acc[p][q]);
            }
        }

        float b0 = bias[o0 + j * 4 + 0];
        float b1 = bias[o0 + j * 4 + 1];
        float b2 = bias[o0 + j * 4 + 2];
        float b3 = bias[o0 + j * 4 + 3];
#pragma unroll
        for (int p = 0; p < 4; ++p) {
            float4 v = make_float4(acc[p][0] + b0, acc[p][1] + b1,
                                   acc[p][2] + b2, acc[p][3] + b3);
            size_t off = ((size_t)b * SS + s0 + i * 4 + p) * COUT + o0 + j * 4;
            *(float4*)&G[off] = v;
        }
    }
}

// ---------------------------------------------------------------------------
// Merge kernel: per query, fold 24 partial candidates (ascending-s order ->
// top_k tie-break preserved), compute weights once, store {w,idx}.
// ---------------------------------------------------------------------------
__global__ __launch_bounds__(256) void k_merge(const float* __restrict__ pd,
                                               const int* __restrict__ pi,
                                               float4* __restrict__ wi4,
                                               int4* __restrict__ gi4) {
    int b = blockIdx.y;
    int n = blockIdx.x * 256 + threadIdx.x;

    float d0 = 3.4e38f, d1 = 3.4e38f, d2 = 3.4e38f;
    int i0 = 0, i1 = 0, i2 = 0;
#pragma unroll
    for (int ch = 0; ch < SC; ++ch) {
        size_t base = ((size_t)(ch * BB + b) * NN + n) * 3;
#pragma unroll
        for (int j = 0; j < 3; ++j) {
            float d = pd[base + j];
            int   s = pi[base + j];
            bool c0 = d < d0, c1 = d < d1, c2 = d < d2;
            d2 = __builtin_amdgcn_fmed3f(d1, d, d2);
            d1 = __builtin_amdgcn_fmed3f(d0, d, d1);
            d0 = fminf(d0, d);
            i2 = c1 ? i1 : (c2 ? s : i2);
            i1 = c0 ? i0 : (c1 ? s : i1);
            i0 = c0 ? s : i0;
        }
    }

    float r0 = 1.0f / (d0 + 1e-8f);
    float r1 = 1.0f / (d1 + 1e-8f);
    float r2 = 1.0f / (d2 + 1e-8f);
    float inv = 1.0f / (r0 + r1 + r2);
    size_t q = (size_t)b * NN + n;
    wi4[q] = make_float4(r0 * inv, r1 * inv, r2 * inv, 0.f);
    gi4[q] = make_int4(i0, i1, i2, 0);
}

// ---------------------------------------------------------------------------
// Output kernel: block = 64 queries, channels processed in 4 chunks of 64.
// Per chunk: phase 1 (lane = channel) coalesced gather of 3 G rows + weighted
// sum into tile[64 q][65] (2 lanes/bank = free; round-5 bug was a full-256
// channel index into a 65-wide tile -- OOB). Phase 2 (lane = n) reads the
// tile transposed (stride 65, conflict-free) and stores coalesced.
// ---------------------------------------------------------------------------
__global__ __launch_bounds__(256) void k_out(const float* __restrict__ G,
                                             const float4* __restrict__ wi4,
                                             const int4* __restrict__ gi4,
                                             float* __restrict__ out) {
    __shared__ float tile[64 * 65];   // 16.6 KB, one 64q x 64o chunk
    __shared__ float sw[64][3];
    __shared__ int   si[64][3];
    int b    = blockIdx.y;
    int n0   = blockIdx.x * 64;
    int t    = threadIdx.x;
    int wave = t >> 6;
    int lane = t & 63;

    if (t < 64) {
        size_t q = (size_t)b * NN + n0 + t;
        float4 wv = wi4[q];
        int4   iv = gi4[q];
        sw[t][0] = wv.x; sw[t][1] = wv.y; sw[t][2] = wv.z;
        si[t][0] = iv.x; si[t][1] = iv.y; si[t][2] = iv.z;
    }
    __syncthreads();

    const float* Gb = G + (size_t)b * SS * COUT;
    float* obase = out + (size_t)b * COUT * NN + n0 + lane;

    for (int oc = 0; oc < 4; ++oc) {
        int o0 = oc * 64;
        // phase 1: lane = channel-in-chunk; each wave covers 16 queries
        for (int qi = wave; qi < 64; qi += 4) {
            float w0 = sw[qi][0], w1 = sw[qi][1], w2 = sw[qi][2];
            const float* r0 = Gb + (size_t)si[qi][0] * COUT + o0;
            const float* r1 = Gb + (size_t)si[qi][1] * COUT + o0;
            const float* r2 = Gb + (size_t)si[qi][2] * COUT + o0;
            tile[qi * 65 + lane] =
                fmaf(w0, r0[lane], fmaf(w1, r1[lane], w2 * r2[lane]));
        }
        __syncthreads();
        // phase 2: lane = n; each wave covers 16 channels of the chunk
#pragma unroll
        for (int j = 0; j < 16; ++j) {
            int c = wave * 16 + j;              // channel-in-chunk
            obase[(size_t)(o0 + c) * NN] = tile[lane * 65 + c];
        }
        __syncthreads();   // tile reused next chunk
    }
}

// ---------------------------------------------------------------------------
extern "C" void kernel_launch(void* const* d_in, const int* in_sizes, int n_in,
                              void* d_out, int out_size, void* d_ws, size_t ws_size,
                              hipStream_t stream) {
    const float* xyz1    = (const float*)d_in[0];   // [B,3,N]
    const float* xyz2    = (const float*)d_in[1];   // [B,3,S]
    const float* points2 = (const float*)d_in[2];   // [B,CIN,S]
    const float* W       = (const float*)d_in[3];   // [COUT,CIN]
    const float* bias    = (const float*)d_in[4];   // [COUT]
    float* out = (float*)d_out;                     // [B,COUT,N]

    char* ws = (char*)d_ws;
    // workspace layout (bytes), total ~31.5 MB:
    //   pd  : 0        .. 6,291,456   ([SC][B][N][3] f32)
    //   pi  : 6291456  .. 12,582,912
    //   G   : 12582912 .. 29,360,128  ([B][S][COUT] f32)
    //   wi4 : 29360128 .. 30,408,704  ([B][N] float4)
    //   gi4 : 30408704 .. 31,457,280  ([B][N] int4)
    float*  pd  = (float*)(ws);
    int*    pi  = (int*)(ws + 6291456);
    float*  G   = (float*)(ws + 12582912);
    float4* wi4 = (float4*)(ws + 29360128);
    int4*   gi4 = (int4*)(ws + 30408704);

    k_fused<<<dim3(KNNB + GEMMB), 256, 0, stream>>>(xyz1, xyz2, points2, W, bias,
                                                    G, pd, pi);
    k_merge<<<dim3(NN / 256, BB), 256, 0, stream>>>(pd, pi, wi4, gi4);
    k_out<<<dim3(NN / 64, BB), 256, 0, stream>>>(G, wi4, gi4, out);
}

// Round 8
// 226.881 us; speedup vs baseline: 1.2535x; 1.2535x over previous
//
#include <hip/hip_runtime.h>

#define BB 4
#define NN 16384
#define SS 4096
#define CIN 256
#define COUT 256

#define SC 8                  // s-chunks for knn
#define SCS (SS / SC)         // 512 points per chunk
#define KNNB ((NN / 512) * SC * BB)           // 32*8*4 = 1024 knn blocks (NPT=2)
#define GEMMB ((COUT / 64) * (SS / 64) * BB)  // 4*64*4 = 1024 gemm blocks

__device__ __forceinline__ unsigned short f2bf(float f) {   // RNE float->bf16
    unsigned u = __float_as_uint(f);
    u += 0x7FFF + ((u >> 16) & 1);
    return (unsigned short)(u >> 16);
}
__device__ __forceinline__ float bf2f(unsigned short h) {
    return __uint_as_float((unsigned)h << 16);
}

// ---------------------------------------------------------------------------
// Fused kernel: blocks [0,KNNB) = partial 3-NN; [KNNB,KNNB+GEMMB) = GEMM
// (round-4 structure: best measured occupancy 66%).
// knn insert = round-6-validated: full-precision d, med3/min distance
// updates + cndmask index updates (15 VALU/pair). NO key packing (round 7
// showed quantized ranking flips near-tie neighbor selection -> O(1) errors).
// ---------------------------------------------------------------------------
__global__ __launch_bounds__(256) void k_fused(const float* __restrict__ xyz1,
                                               const float* __restrict__ xyz2,
                                               const float* __restrict__ P,
                                               const float* __restrict__ W,
                                               const float* __restrict__ bias,
                                               unsigned short* __restrict__ Gh,
                                               float* __restrict__ pd,
                                               int* __restrict__ pi) {
    __shared__ float smem[2112];   // 8.25 KB: knn 512 float4 (8 KB); gemm sP+sW
    int bid = blockIdx.x;
    int t   = threadIdx.x;

    if (bid < KNNB) {
        // ---------------- knn path (NPT=2) ----------------
        int nb = bid & 31;             // 32 n-blocks (512 queries each)
        int ch = (bid >> 5) & 7;       // 8 chunks
        int b  = bid >> 8;
        int s0 = ch * SCS;

        float4* smv = (float4*)smem;   // 512 float4
        const float* x2 = xyz2 + (size_t)b * 3 * SS;
        for (int i = t; i < SCS; i += 256) {
            float px = x2[s0 + i];
            float py = x2[SS + s0 + i];
            float pz = x2[2 * SS + s0 + i];
            smv[i] = make_float4(px, py, pz, fmaf(px, px, fmaf(py, py, pz * pz)));
        }
        __syncthreads();

        int n0  = nb * 512 + t;        // query A
        int n1q = n0 + 256;            // query B
        const float* xb = xyz1 + (size_t)b * 3 * NN;
        float ax = xb[n0],  ay = xb[NN + n0],  az = xb[2 * NN + n0];
        float bx = xb[n1q], by = xb[NN + n1q], bz = xb[2 * NN + n1q];
        float an1 = fmaf(ax, ax, fmaf(ay, ay, az * az));
        float bn1 = fmaf(bx, bx, fmaf(by, by, bz * bz));
        float axm2 = -2.0f * ax, aym2 = -2.0f * ay, azm2 = -2.0f * az;
        float bxm2 = -2.0f * bx, bym2 = -2.0f * by, bzm2 = -2.0f * bz;

        float Ad0 = 3.4e38f, Ad1 = 3.4e38f, Ad2 = 3.4e38f;
        float Bd0 = 3.4e38f, Bd1 = 3.4e38f, Bd2 = 3.4e38f;
        int Ai0 = 0, Ai1 = 0, Ai2 = 0;
        int Bi0 = 0, Bi1 = 0, Bi2 = 0;

#pragma unroll 8
        for (int s = 0; s < SCS; ++s) {
            float4 p = smv[s];
            int gs = s0 + s;
            {   // full d = -2*dot + |p2|^2 + |p1|^2 (round-6-validated form)
                float d = fmaf(p.x, axm2, fmaf(p.y, aym2,
                          fmaf(p.z, azm2, p.w + an1)));
                bool c0 = d < Ad0, c1 = d < Ad1, c2 = d < Ad2;
                Ad2 = __builtin_amdgcn_fmed3f(Ad1, d, Ad2);
                Ad1 = __builtin_amdgcn_fmed3f(Ad0, d, Ad1);
                Ad0 = fminf(Ad0, d);
                Ai2 = c1 ? Ai1 : (c2 ? gs : Ai2);
                Ai1 = c0 ? Ai0 : (c1 ? gs : Ai1);
                Ai0 = c0 ? gs : Ai0;
            }
            {
                float d = fmaf(p.x, bxm2, fmaf(p.y, bym2,
                          fmaf(p.z, bzm2, p.w + bn1)));
                bool c0 = d < Bd0, c1 = d < Bd1, c2 = d < Bd2;
                Bd2 = __builtin_amdgcn_fmed3f(Bd1, d, Bd2);
                Bd1 = __builtin_amdgcn_fmed3f(Bd0, d, Bd1);
                Bd0 = fminf(Bd0, d);
                Bi2 = c1 ? Bi1 : (c2 ? gs : Bi2);
                Bi1 = c0 ? Bi0 : (c1 ? gs : Bi1);
                Bi0 = c0 ? gs : Bi0;
            }
        }

        // layout [ch][b][j][n] -> coalesced stores and merge-loads
        size_t cb = (size_t)(ch * BB + b) * 3;
        pd[(cb + 0) * NN + n0]  = Ad0;  pd[(cb + 1) * NN + n0]  = Ad1;
        pd[(cb + 2) * NN + n0]  = Ad2;
        pi[(cb + 0) * NN + n0]  = Ai0;  pi[(cb + 1) * NN + n0]  = Ai1;
        pi[(cb + 2) * NN + n0]  = Ai2;
        pd[(cb + 0) * NN + n1q] = Bd0;  pd[(cb + 1) * NN + n1q] = Bd1;
        pd[(cb + 2) * NN + n1q] = Bd2;
        pi[(cb + 0) * NN + n1q] = Bi0;  pi[(cb + 1) * NN + n1q] = Bi1;
        pi[(cb + 2) * NN + n1q] = Bi2;
    } else {
        // ---------------- gemm path: 64s x 64o tile, 4x4 micro ----------
        int g  = bid - KNNB;
        int o0 = (g & 3) * 64;
        int s0 = ((g >> 2) & 63) * 64;
        int b  = g >> 8;
        float* sP = smem;              // 16 x 64
        float* sW = smem + 1024;       // 16 x 68 (padded)
        int i = t & 15;
        int j = t >> 4;

        float acc[4][4];
#pragma unroll
        for (int p = 0; p < 4; ++p)
#pragma unroll
            for (int q = 0; q < 4; ++q) acc[p][q] = 0.f;

        const float* Pb = P + (size_t)b * CIN * SS;

        for (int c0 = 0; c0 < CIN; c0 += 16) {
            __syncthreads();
            {
                int col = t & 63;
                int r0r = t >> 6;
#pragma unroll
                for (int r = 0; r < 4; ++r) {
                    int row = r0r + r * 4;
                    sP[row * 64 + col] = Pb[(size_t)(c0 + row) * SS + s0 + col];
                }
            }
            {
                int cc = t & 15;
                int obase = t >> 4;
#pragma unroll
                for (int r = 0; r < 4; ++r) {
                    int oo = obase + 16 * r;
                    sW[cc * 68 + oo] = W[(size_t)(o0 + oo) * CIN + c0 + cc];
                }
            }
            __syncthreads();

#pragma unroll
            for (int cc = 0; cc < 16; ++cc) {
                float4 a  = *(const float4*)&sP[cc * 64 + i * 4];
                float4 bv = *(const float4*)&sW[cc * 68 + j * 4];
                float av[4] = {a.x, a.y, a.z, a.w};
                float bw[4] = {bv.x, bv.y, bv.z, bv.w};
#pragma unroll
                for (int p = 0; p < 4; ++p)
#pragma unroll
                    for (int q = 0; q < 4; ++q)
                        acc[p][q] = fmaf(av[p], bw[q], acc[p][q]);
            }
        }

        float b0 = bias[o0 + j * 4 + 0];
        float b1 = bias[o0 + j * 4 + 1];
        float b2 = bias[o0 + j * 4 + 2];
        float b3 = bias[o0 + j * 4 + 3];
#pragma unroll
        for (int p = 0; p < 4; ++p) {
            ushort4 v;
            v.x = f2bf(acc[p][0] + b0);
            v.y = f2bf(acc[p][1] + b1);
            v.z = f2bf(acc[p][2] + b2);
            v.w = f2bf(acc[p][3] + b3);
            size_t off = ((size_t)b * SS + s0 + i * 4 + p) * COUT + o0 + j * 4;
            *(ushort4*)&Gh[off] = v;
        }
    }
}

// ---------------------------------------------------------------------------
// Output kernel: block = 64 queries.
// Preamble: exact 24-candidate merge (stage 1: lane=q, wave g folds chunks
// 2g,2g+1; stage 2: fold 4 partials). Candidate order = ascending global s
// at every stage -> top_k stable tie-break preserved. Full-precision d.
// Then 4 chunks of 64 channels: phase 1 (lane=channel) bf16 gather + blend
// into tile[64][65]; phase 2 (lane=n) transposed read, coalesced store.
// ---------------------------------------------------------------------------
__global__ __launch_bounds__(256) void k_out(const unsigned short* __restrict__ Gh,
                                             const float* __restrict__ pd,
                                             const int* __restrict__ pi,
                                             float* __restrict__ out) {
    __shared__ float tile[64 * 65];   // 16.6 KB
    __shared__ float ptd[64][12];
    __shared__ int   pti[64][12];
    __shared__ float sw[64][3];
    __shared__ int   si[64][3];
    int b    = blockIdx.y;
    int n0   = blockIdx.x * 64;
    int t    = threadIdx.x;
    int wave = t >> 6;
    int lane = t & 63;

    // stage 1: thread (q=lane, g=wave) folds chunks 2g, 2g+1 (6 candidates)
    {
        int n = n0 + lane;
        float d0 = 3.4e38f, d1 = 3.4e38f, d2 = 3.4e38f;
        int i0 = 0, i1 = 0, i2 = 0;
#pragma unroll
        for (int c = 0; c < 2; ++c) {
            size_t cb = (size_t)((wave * 2 + c) * BB + b) * 3;
#pragma unroll
            for (int j = 0; j < 3; ++j) {
                float d = pd[(cb + j) * NN + n];
                int   s = pi[(cb + j) * NN + n];
                bool c0 = d < d0, c1 = d < d1, c2 = d < d2;
                d2 = __builtin_amdgcn_fmed3f(d1, d, d2);
                d1 = __builtin_amdgcn_fmed3f(d0, d, d1);
                d0 = fminf(d0, d);
                i2 = c1 ? i1 : (c2 ? s : i2);
                i1 = c0 ? i0 : (c1 ? s : i1);
                i0 = c0 ? s : i0;
            }
        }
        ptd[lane][wave * 3 + 0] = d0; pti[lane][wave * 3 + 0] = i0;
        ptd[lane][wave * 3 + 1] = d1; pti[lane][wave * 3 + 1] = i1;
        ptd[lane][wave * 3 + 2] = d2; pti[lane][wave * 3 + 2] = i2;
    }
    __syncthreads();
    // stage 2: threads 0..63 fold the 4 partial triples (ascending g order)
    if (t < 64) {
        float d0 = 3.4e38f, d1 = 3.4e38f, d2 = 3.4e38f;
        int i0 = 0, i1 = 0, i2 = 0;
#pragma unroll
        for (int c = 0; c < 12; ++c) {
            float d = ptd[t][c];
            int   s = pti[t][c];
            bool c0 = d < d0, c1 = d < d1, c2 = d < d2;
            d2 = __builtin_amdgcn_fmed3f(d1, d, d2);
            d1 = __builtin_amdgcn_fmed3f(d0, d, d1);
            d0 = fminf(d0, d);
            i2 = c1 ? i1 : (c2 ? s : i2);
            i1 = c0 ? i0 : (c1 ? s : i1);
            i0 = c0 ? s : i0;
        }
        float r0 = 1.0f / (d0 + 1e-8f);
        float r1 = 1.0f / (d1 + 1e-8f);
        float r2 = 1.0f / (d2 + 1e-8f);
        float inv = 1.0f / (r0 + r1 + r2);
        sw[t][0] = r0 * inv; sw[t][1] = r1 * inv; sw[t][2] = r2 * inv;
        si[t][0] = i0;       si[t][1] = i1;       si[t][2] = i2;
    }
    __syncthreads();

    const unsigned short* Gb = Gh + (size_t)b * SS * COUT;
    float* obase = out + (size_t)b * COUT * NN + n0 + lane;

    for (int oc = 0; oc < 4; ++oc) {
        int o0 = oc * 64;
        // phase 1: lane = channel-in-chunk; each wave covers 16 queries
#pragma unroll 4
        for (int qi = wave; qi < 64; qi += 4) {
            float w0 = sw[qi][0], w1 = sw[qi][1], w2 = sw[qi][2];
            const unsigned short* r0 = Gb + (size_t)si[qi][0] * COUT + o0;
            const unsigned short* r1 = Gb + (size_t)si[qi][1] * COUT + o0;
            const unsigned short* r2 = Gb + (size_t)si[qi][2] * COUT + o0;
            tile[qi * 65 + lane] = fmaf(w0, bf2f(r0[lane]),
                                   fmaf(w1, bf2f(r1[lane]),
                                        w2 * bf2f(r2[lane])));
        }
        __syncthreads();
        // phase 2: lane = n; each wave covers 16 channels of the chunk
#pragma unroll
        for (int j = 0; j < 16; ++j) {
            int c = wave * 16 + j;
            obase[(size_t)(o0 + c) * NN] = tile[lane * 65 + c];
        }
        __syncthreads();
    }
}

// ---------------------------------------------------------------------------
extern "C" void kernel_launch(void* const* d_in, const int* in_sizes, int n_in,
                              void* d_out, int out_size, void* d_ws, size_t ws_size,
                              hipStream_t stream) {
    const float* xyz1    = (const float*)d_in[0];   // [B,3,N]
    const float* xyz2    = (const float*)d_in[1];   // [B,3,S]
    const float* points2 = (const float*)d_in[2];   // [B,CIN,S]
    const float* W       = (const float*)d_in[3];   // [COUT,CIN]
    const float* bias    = (const float*)d_in[4];   // [COUT]
    float* out = (float*)d_out;                     // [B,COUT,N]

    char* ws = (char*)d_ws;
    // workspace layout (bytes), total 20 MB:
    //   pd : 0        .. 6,291,456   ([SC][B][3][N] f32)
    //   pi : 6291456  .. 12,582,912  ([SC][B][3][N] i32)
    //   Gh : 12582912 .. 20,971,520  ([B][S][COUT] bf16)
    float*          pd = (float*)(ws);
    int*            pi = (int*)(ws + 6291456);
    unsigned short* Gh = (unsigned short*)(ws + 12582912);

    k_fused<<<dim3(KNNB + GEMMB), 256, 0, stream>>>(xyz1, xyz2, points2, W, bias,
                                                    Gh, pd, pi);
    k_out<<<dim3(NN / 64, BB), 256, 0, stream>>>(Gh, pd, pi, out);
}

// Round 9
// 224.538 us; speedup vs baseline: 1.2666x; 1.0104x over previous
//
#include <hip/hip_runtime.h>

#define BB 4
#define NN 16384
#define SS 4096
#define CIN 256
#define COUT 256

#define SC 8                  // s-chunks for knn
#define SCS (SS / SC)         // 512 points per chunk
#define KNNB ((NN / 512) * SC * BB)           // 32*8*4 = 1024 knn blocks (NPT=2)
#define GEMMB ((COUT / 64) * (SS / 64) * BB)  // 4*64*4 = 1024 gemm blocks

__device__ __forceinline__ unsigned short f2bf(float f) {   // RNE float->bf16
    unsigned u = __float_as_uint(f);
    u += 0x7FFF + ((u >> 16) & 1);
    return (unsigned short)(u >> 16);
}
__device__ __forceinline__ float bf2f(unsigned short h) {
    return __uint_as_float((unsigned)h << 16);
}

// ---------------------------------------------------------------------------
// Fused kernel: blocks [0,KNNB) = partial 3-NN; [KNNB,..) = GEMM.
// knn: e-form distance (3 fma/pair; |p1|^2 added at store — R4/R6-validated),
// med3/min distance updates + cndmask index updates = 14 VALU/pair.
// ---------------------------------------------------------------------------
__global__ __launch_bounds__(256) void k_fused(const float* __restrict__ xyz1,
                                               const float* __restrict__ xyz2,
                                               const float* __restrict__ P,
                                               const float* __restrict__ W,
                                               const float* __restrict__ bias,
                                               unsigned short* __restrict__ Gh,
                                               float* __restrict__ pd,
                                               int* __restrict__ pi) {
    __shared__ float smem[2112];   // 8.25 KB: knn 512 float4; gemm sP+sW
    int bid = blockIdx.x;
    int t   = threadIdx.x;

    if (bid < KNNB) {
        // ---------------- knn path (NPT=2) ----------------
        int nb = bid & 31;
        int ch = (bid >> 5) & 7;
        int b  = bid >> 8;
        int s0 = ch * SCS;

        float4* smv = (float4*)smem;
        const float* x2 = xyz2 + (size_t)b * 3 * SS;
        for (int i = t; i < SCS; i += 256) {
            float px = x2[s0 + i];
            float py = x2[SS + s0 + i];
            float pz = x2[2 * SS + s0 + i];
            smv[i] = make_float4(px, py, pz, fmaf(px, px, fmaf(py, py, pz * pz)));
        }
        __syncthreads();

        int n0  = nb * 512 + t;
        int n1q = n0 + 256;
        const float* xb = xyz1 + (size_t)b * 3 * NN;
        float ax = xb[n0],  ay = xb[NN + n0],  az = xb[2 * NN + n0];
        float bx = xb[n1q], by = xb[NN + n1q], bz = xb[2 * NN + n1q];
        float an1 = fmaf(ax, ax, fmaf(ay, ay, az * az));
        float bn1 = fmaf(bx, bx, fmaf(by, by, bz * bz));
        float axm2 = -2.0f * ax, aym2 = -2.0f * ay, azm2 = -2.0f * az;
        float bxm2 = -2.0f * bx, bym2 = -2.0f * by, bzm2 = -2.0f * bz;

        float Ad0 = 3.4e38f, Ad1 = 3.4e38f, Ad2 = 3.4e38f;
        float Bd0 = 3.4e38f, Bd1 = 3.4e38f, Bd2 = 3.4e38f;
        int Ai0 = 0, Ai1 = 0, Ai2 = 0;
        int Bi0 = 0, Bi1 = 0, Bi2 = 0;

#pragma unroll 8
        for (int s = 0; s < SCS; ++s) {
            float4 p = smv[s];
            int gs = s0 + s;
            {   // e = -2*dot + |p2|^2 ; ranking invariant to +|p1|^2 shift
                float e = fmaf(p.x, axm2, fmaf(p.y, aym2, fmaf(p.z, azm2, p.w)));
                bool c0 = e < Ad0, c1 = e < Ad1, c2 = e < Ad2;
                Ad2 = __builtin_amdgcn_fmed3f(Ad1, e, Ad2);
                Ad1 = __builtin_amdgcn_fmed3f(Ad0, e, Ad1);
                Ad0 = fminf(Ad0, e);
                Ai2 = c1 ? Ai1 : (c2 ? gs : Ai2);
                Ai1 = c0 ? Ai0 : (c1 ? gs : Ai1);
                Ai0 = c0 ? gs : Ai0;
            }
            {
                float e = fmaf(p.x, bxm2, fmaf(p.y, bym2, fmaf(p.z, bzm2, p.w)));
                bool c0 = e < Bd0, c1 = e < Bd1, c2 = e < Bd2;
                Bd2 = __builtin_amdgcn_fmed3f(Bd1, e, Bd2);
                Bd1 = __builtin_amdgcn_fmed3f(Bd0, e, Bd1);
                Bd0 = fminf(Bd0, e);
                Bi2 = c1 ? Bi1 : (c2 ? gs : Bi2);
                Bi1 = c0 ? Bi0 : (c1 ? gs : Bi1);
                Bi0 = c0 ? gs : Bi0;
            }
        }

        // layout [ch][b][j][n]; d = e + |p1|^2
        size_t cb = (size_t)(ch * BB + b) * 3;
        pd[(cb + 0) * NN + n0]  = Ad0 + an1;  pd[(cb + 1) * NN + n0]  = Ad1 + an1;
        pd[(cb + 2) * NN + n0]  = Ad2 + an1;
        pi[(cb + 0) * NN + n0]  = Ai0;  pi[(cb + 1) * NN + n0]  = Ai1;
        pi[(cb + 2) * NN + n0]  = Ai2;
        pd[(cb + 0) * NN + n1q] = Bd0 + bn1;  pd[(cb + 1) * NN + n1q] = Bd1 + bn1;
        pd[(cb + 2) * NN + n1q] = Bd2 + bn1;
        pi[(cb + 0) * NN + n1q] = Bi0;  pi[(cb + 1) * NN + n1q] = Bi1;
        pi[(cb + 2) * NN + n1q] = Bi2;
    } else {
        // ---------------- gemm path: 64s x 64o tile, 4x4 micro ----------
        int g  = bid - KNNB;
        int o0 = (g & 3) * 64;
        int s0 = ((g >> 2) & 63) * 64;
        int b  = g >> 8;
        float* sP = smem;              // 16 x 64
        float* sW = smem + 1024;       // 16 x 68 (padded)
        int i = t & 15;
        int j = t >> 4;

        float acc[4][4];
#pragma unroll
        for (int p = 0; p < 4; ++p)
#pragma unroll
            for (int q = 0; q < 4; ++q) acc[p][q] = 0.f;

        const float* Pb = P + (size_t)b * CIN * SS;

        for (int c0 = 0; c0 < CIN; c0 += 16) {
            __syncthreads();
            {
                int col = t & 63;
                int r0r = t >> 6;
#pragma unroll
                for (int r = 0; r < 4; ++r) {
                    int row = r0r + r * 4;
                    sP[row * 64 + col] = Pb[(size_t)(c0 + row) * SS + s0 + col];
                }
            }
            {
                int cc = t & 15;
                int obase = t >> 4;
#pragma unroll
                for (int r = 0; r < 4; ++r) {
                    int oo = obase + 16 * r;
                    sW[cc * 68 + oo] = W[(size_t)(o0 + oo) * CIN + c0 + cc];
                }
            }
            __syncthreads();

#pragma unroll
            for (int cc = 0; cc < 16; ++cc) {
                float4 a  = *(const float4*)&sP[cc * 64 + i * 4];
                float4 bv = *(const float4*)&sW[cc * 68 + j * 4];
                float av[4] = {a.x, a.y, a.z, a.w};
                float bw[4] = {bv.x, bv.y, bv.z, bv.w};
#pragma unroll
                for (int p = 0; p < 4; ++p)
#pragma unroll
                    for (int q = 0; q < 4; ++q)
                        acc[p][q] = fmaf(av[p], bw[q], acc[p][q]);
            }
        }

        float b0 = bias[o0 + j * 4 + 0];
        float b1 = bias[o0 + j * 4 + 1];
        float b2 = bias[o0 + j * 4 + 2];
        float b3 = bias[o0 + j * 4 + 3];
#pragma unroll
        for (int p = 0; p < 4; ++p) {
            ushort4 v;
            v.x = f2bf(acc[p][0] + b0);
            v.y = f2bf(acc[p][1] + b1);
            v.z = f2bf(acc[p][2] + b2);
            v.w = f2bf(acc[p][3] + b3);
            size_t off = ((size_t)b * SS + s0 + i * 4 + p) * COUT + o0 + j * 4;
            *(ushort4*)&Gh[off] = v;
        }
    }
}

// ---------------------------------------------------------------------------
// Merge: per query, flat fold of 24 candidates in ascending (ch, j) order
// (= ascending global s -> top_k stable tie-break), weights once -> wi4/gi4.
// ---------------------------------------------------------------------------
__global__ __launch_bounds__(256) void k_merge(const float* __restrict__ pd,
                                               const int* __restrict__ pi,
                                               float4* __restrict__ wi4,
                                               int4* __restrict__ gi4) {
    int b = blockIdx.y;
    int n = blockIdx.x * 256 + threadIdx.x;

    float d0 = 3.4e38f, d1 = 3.4e38f, d2 = 3.4e38f;
    int i0 = 0, i1 = 0, i2 = 0;
#pragma unroll
    for (int ch = 0; ch < SC; ++ch) {
        size_t cb = (size_t)(ch * BB + b) * 3;
#pragma unroll
        for (int j = 0; j < 3; ++j) {
            float d = pd[(cb + j) * NN + n];
            int   s = pi[(cb + j) * NN + n];
            bool c0 = d < d0, c1 = d < d1, c2 = d < d2;
            d2 = __builtin_amdgcn_fmed3f(d1, d, d2);
            d1 = __builtin_amdgcn_fmed3f(d0, d, d1);
            d0 = fminf(d0, d);
            i2 = c1 ? i1 : (c2 ? s : i2);
            i1 = c0 ? i0 : (c1 ? s : i1);
            i0 = c0 ? s : i0;
        }
    }

    float r0 = 1.0f / (d0 + 1e-8f);
    float r1 = 1.0f / (d1 + 1e-8f);
    float r2 = 1.0f / (d2 + 1e-8f);
    float inv = 1.0f / (r0 + r1 + r2);
    size_t q = (size_t)b * NN + n;
    wi4[q] = make_float4(r0 * inv, r1 * inv, r2 * inv, 0.f);
    gi4[q] = make_int4(i0, i1, i2, 0);
}

// ---------------------------------------------------------------------------
// Output: grid (NN/64, 4 o-chunks, B) = 4096 blocks; block = 64 q x 64 ch.
// Phase 1: wave handles 4 queries (qg=lane>>4) x 64 ch; each lane loads
// ushort4 (8B) from each of 3 G rows -> 3 loads per wave-pass cover 4
// queries (4x fewer load insts, 4x bytes/vmcnt slot vs round 8); all 4
// passes unrolled -> 12 outstanding loads/lane. Tile stride 68 floats:
// 16B-aligned b128 LDS ops in both phases.
// Phase 2: lane=n, b128 tile reads (4 ch), coalesced NN-strided stores.
// ---------------------------------------------------------------------------
__global__ __launch_bounds__(256) void k_out(const unsigned short* __restrict__ Gh,
                                             const float4* __restrict__ wi4,
                                             const int4* __restrict__ gi4,
                                             float* __restrict__ out) {
    __shared__ float  tile[64 * 68];   // 17.4 KB
    __shared__ float4 swv[64];
    __shared__ int4   siv[64];
    int b    = blockIdx.z;
    int oc   = blockIdx.y;
    int n0   = blockIdx.x * 64;
    int o0   = oc * 64;
    int t    = threadIdx.x;
    int wave = t >> 6;
    int lane = t & 63;
    int qg   = lane >> 4;     // query-in-group 0..3
    int c16  = lane & 15;     // channel quad 0..15

    if (t < 64) {
        size_t q = (size_t)b * NN + n0 + t;
        swv[t] = wi4[q];
        siv[t] = gi4[q];
    }
    __syncthreads();

    const unsigned short* Gb = Gh + (size_t)b * SS * COUT;

#pragma unroll
    for (int pass = 0; pass < 4; ++pass) {
        int q = pass * 16 + wave * 4 + qg;
        float4 wv = swv[q];
        int4   iv = siv[q];
        int co = o0 + c16 * 4;
        ushort4 a0 = *(const ushort4*)(Gb + (size_t)iv.x * COUT + co);
        ushort4 a1 = *(const ushort4*)(Gb + (size_t)iv.y * COUT + co);
        ushort4 a2 = *(const ushort4*)(Gb + (size_t)iv.z * COUT + co);
        float4 v;
        v.x = fmaf(wv.x, bf2f(a0.x), fmaf(wv.y, bf2f(a1.x), wv.z * bf2f(a2.x)));
        v.y = fmaf(wv.x, bf2f(a0.y), fmaf(wv.y, bf2f(a1.y), wv.z * bf2f(a2.y)));
        v.z = fmaf(wv.x, bf2f(a0.z), fmaf(wv.y, bf2f(a1.z), wv.z * bf2f(a2.z)));
        v.w = fmaf(wv.x, bf2f(a0.w), fmaf(wv.y, bf2f(a1.w), wv.z * bf2f(a2.w)));
        *(float4*)&tile[q * 68 + c16 * 4] = v;
    }
    __syncthreads();

    float* obase = out + ((size_t)b * COUT + o0) * NN + n0 + lane;
#pragma unroll
    for (int g = 0; g < 4; ++g) {
        int c = wave * 16 + g * 4;
        float4 v = *(const float4*)&tile[lane * 68 + c];
        obase[(size_t)(c + 0) * NN] = v.x;
        obase[(size_t)(c + 1) * NN] = v.y;
        obase[(size_t)(c + 2) * NN] = v.z;
        obase[(size_t)(c + 3) * NN] = v.w;
    }
}

// ---------------------------------------------------------------------------
extern "C" void kernel_launch(void* const* d_in, const int* in_sizes, int n_in,
                              void* d_out, int out_size, void* d_ws, size_t ws_size,
                              hipStream_t stream) {
    const float* xyz1    = (const float*)d_in[0];   // [B,3,N]
    const float* xyz2    = (const float*)d_in[1];   // [B,3,S]
    const float* points2 = (const float*)d_in[2];   // [B,CIN,S]
    const float* W       = (const float*)d_in[3];   // [COUT,CIN]
    const float* bias    = (const float*)d_in[4];   // [COUT]
    float* out = (float*)d_out;                     // [B,COUT,N]

    char* ws = (char*)d_ws;
    // workspace layout (bytes), total ~23 MB:
    //   pd  : 0        .. 6,291,456   ([SC][B][3][N] f32)
    //   pi  : 6291456  .. 12,582,912  ([SC][B][3][N] i32)
    //   Gh  : 12582912 .. 20,971,520  ([B][S][COUT] bf16)
    //   wi4 : 20971520 .. 22,020,096  ([B][N] float4)
    //   gi4 : 22020096 .. 23,068,672  ([B][N] int4)
    float*          pd  = (float*)(ws);
    int*            pi  = (int*)(ws + 6291456);
    unsigned short* Gh  = (unsigned short*)(ws + 12582912);
    float4*         wi4 = (float4*)(ws + 20971520);
    int4*           gi4 = (int4*)(ws + 22020096);

    k_fused<<<dim3(KNNB + GEMMB), 256, 0, stream>>>(xyz1, xyz2, points2, W, bias,
                                                    Gh, pd, pi);
    k_merge<<<dim3(NN / 256, BB), 256, 0, stream>>>(pd, pi, wi4, gi4);
    k_out<<<dim3(NN / 64, 4, BB), 256, 0, stream>>>(Gh, wi4, gi4, out);
}

// Round 10
// 220.754 us; speedup vs baseline: 1.2883x; 1.0171x over previous
//
#include <hip/hip_runtime.h>

#define BB 4
#define NN 16384
#define SS 4096
#define CIN 256
#define COUT 256

#define SC 8                  // s-chunks for knn
#define SCS (SS / SC)         // 512 points per chunk
#define KNNB ((NN / 512) * SC * BB)           // 32*8*4 = 1024 knn blocks (NPT=2)
#define GEMMB ((COUT / 64) * (SS / 64) * BB)  // 4*64*4 = 1024 gemm blocks

__device__ __forceinline__ unsigned short f2bf(float f) {   // RNE float->bf16
    unsigned u = __float_as_uint(f);
    u += 0x7FFF + ((u >> 16) & 1);
    return (unsigned short)(u >> 16);
}
__device__ __forceinline__ float bf2f(unsigned short h) {
    return __uint_as_float((unsigned)h << 16);
}

// ---------------------------------------------------------------------------
// Fused kernel: blocks [0,KNNB) = partial 3-NN; [KNNB,..) = GEMM.
// (unchanged from round 9: 140 us, best measured)
// ---------------------------------------------------------------------------
__global__ __launch_bounds__(256) void k_fused(const float* __restrict__ xyz1,
                                               const float* __restrict__ xyz2,
                                               const float* __restrict__ P,
                                               const float* __restrict__ W,
                                               const float* __restrict__ bias,
                                               unsigned short* __restrict__ Gh,
                                               float* __restrict__ pd,
                                               int* __restrict__ pi) {
    __shared__ float smem[2112];   // 8.25 KB: knn 512 float4; gemm sP+sW
    int bid = blockIdx.x;
    int t   = threadIdx.x;

    if (bid < KNNB) {
        // ---------------- knn path (NPT=2) ----------------
        int nb = bid & 31;
        int ch = (bid >> 5) & 7;
        int b  = bid >> 8;
        int s0 = ch * SCS;

        float4* smv = (float4*)smem;
        const float* x2 = xyz2 + (size_t)b * 3 * SS;
        for (int i = t; i < SCS; i += 256) {
            float px = x2[s0 + i];
            float py = x2[SS + s0 + i];
            float pz = x2[2 * SS + s0 + i];
            smv[i] = make_float4(px, py, pz, fmaf(px, px, fmaf(py, py, pz * pz)));
        }
        __syncthreads();

        int n0  = nb * 512 + t;
        int n1q = n0 + 256;
        const float* xb = xyz1 + (size_t)b * 3 * NN;
        float ax = xb[n0],  ay = xb[NN + n0],  az = xb[2 * NN + n0];
        float bx = xb[n1q], by = xb[NN + n1q], bz = xb[2 * NN + n1q];
        float an1 = fmaf(ax, ax, fmaf(ay, ay, az * az));
        float bn1 = fmaf(bx, bx, fmaf(by, by, bz * bz));
        float axm2 = -2.0f * ax, aym2 = -2.0f * ay, azm2 = -2.0f * az;
        float bxm2 = -2.0f * bx, bym2 = -2.0f * by, bzm2 = -2.0f * bz;

        float Ad0 = 3.4e38f, Ad1 = 3.4e38f, Ad2 = 3.4e38f;
        float Bd0 = 3.4e38f, Bd1 = 3.4e38f, Bd2 = 3.4e38f;
        int Ai0 = 0, Ai1 = 0, Ai2 = 0;
        int Bi0 = 0, Bi1 = 0, Bi2 = 0;

#pragma unroll 8
        for (int s = 0; s < SCS; ++s) {
            float4 p = smv[s];
            int gs = s0 + s;
            {   // e = -2*dot + |p2|^2 ; ranking invariant to +|p1|^2 shift
                float e = fmaf(p.x, axm2, fmaf(p.y, aym2, fmaf(p.z, azm2, p.w)));
                bool c0 = e < Ad0, c1 = e < Ad1, c2 = e < Ad2;
                Ad2 = __builtin_amdgcn_fmed3f(Ad1, e, Ad2);
                Ad1 = __builtin_amdgcn_fmed3f(Ad0, e, Ad1);
                Ad0 = fminf(Ad0, e);
                Ai2 = c1 ? Ai1 : (c2 ? gs : Ai2);
                Ai1 = c0 ? Ai0 : (c1 ? gs : Ai1);
                Ai0 = c0 ? gs : Ai0;
            }
            {
                float e = fmaf(p.x, bxm2, fmaf(p.y, bym2, fmaf(p.z, bzm2, p.w)));
                bool c0 = e < Bd0, c1 = e < Bd1, c2 = e < Bd2;
                Bd2 = __builtin_amdgcn_fmed3f(Bd1, e, Bd2);
                Bd1 = __builtin_amdgcn_fmed3f(Bd0, e, Bd1);
                Bd0 = fminf(Bd0, e);
                Bi2 = c1 ? Bi1 : (c2 ? gs : Bi2);
                Bi1 = c0 ? Bi0 : (c1 ? gs : Bi1);
                Bi0 = c0 ? gs : Bi0;
            }
        }

        // layout [ch][b][j][n]; d = e + |p1|^2
        size_t cb = (size_t)(ch * BB + b) * 3;
        pd[(cb + 0) * NN + n0]  = Ad0 + an1;  pd[(cb + 1) * NN + n0]  = Ad1 + an1;
        pd[(cb + 2) * NN + n0]  = Ad2 + an1;
        pi[(cb + 0) * NN + n0]  = Ai0;  pi[(cb + 1) * NN + n0]  = Ai1;
        pi[(cb + 2) * NN + n0]  = Ai2;
        pd[(cb + 0) * NN + n1q] = Bd0 + bn1;  pd[(cb + 1) * NN + n1q] = Bd1 + bn1;
        pd[(cb + 2) * NN + n1q] = Bd2 + bn1;
        pi[(cb + 0) * NN + n1q] = Bi0;  pi[(cb + 1) * NN + n1q] = Bi1;
        pi[(cb + 2) * NN + n1q] = Bi2;
    } else {
        // ---------------- gemm path: 64s x 64o tile, 4x4 micro ----------
        int g  = bid - KNNB;
        int o0 = (g & 3) * 64;
        int s0 = ((g >> 2) & 63) * 64;
        int b  = g >> 8;
        float* sP = smem;              // 16 x 64
        float* sW = smem + 1024;       // 16 x 68 (padded)
        int i = t & 15;
        int j = t >> 4;

        float acc[4][4];
#pragma unroll
        for (int p = 0; p < 4; ++p)
#pragma unroll
            for (int q = 0; q < 4; ++q) acc[p][q] = 0.f;

        const float* Pb = P + (size_t)b * CIN * SS;

        for (int c0 = 0; c0 < CIN; c0 += 16) {
            __syncthreads();
            {
                int col = t & 63;
                int r0r = t >> 6;
#pragma unroll
                for (int r = 0; r < 4; ++r) {
                    int row = r0r + r * 4;
                    sP[row * 64 + col] = Pb[(size_t)(c0 + row) * SS + s0 + col];
                }
            }
            {
                int cc = t & 15;
                int obase = t >> 4;
#pragma unroll
                for (int r = 0; r < 4; ++r) {
                    int oo = obase + 16 * r;
                    sW[cc * 68 + oo] = W[(size_t)(o0 + oo) * CIN + c0 + cc];
                }
            }
            __syncthreads();

#pragma unroll
            for (int cc = 0; cc < 16; ++cc) {
                float4 a  = *(const float4*)&sP[cc * 64 + i * 4];
                float4 bv = *(const float4*)&sW[cc * 68 + j * 4];
                float av[4] = {a.x, a.y, a.z, a.w};
                float bw[4] = {bv.x, bv.y, bv.z, bv.w};
#pragma unroll
                for (int p = 0; p < 4; ++p)
#pragma unroll
                    for (int q = 0; q < 4; ++q)
                        acc[p][q] = fmaf(av[p], bw[q], acc[p][q]);
            }
        }

        float b0 = bias[o0 + j * 4 + 0];
        float b1 = bias[o0 + j * 4 + 1];
        float b2 = bias[o0 + j * 4 + 2];
        float b3 = bias[o0 + j * 4 + 3];
#pragma unroll
        for (int p = 0; p < 4; ++p) {
            ushort4 v;
            v.x = f2bf(acc[p][0] + b0);
            v.y = f2bf(acc[p][1] + b1);
            v.z = f2bf(acc[p][2] + b2);
            v.w = f2bf(acc[p][3] + b3);
            size_t off = ((size_t)b * SS + s0 + i * 4 + p) * COUT + o0 + j * 4;
            *(ushort4*)&Gh[off] = v;
        }
    }
}

// ---------------------------------------------------------------------------
// Merge: unchanged from round 9.
// ---------------------------------------------------------------------------
__global__ __launch_bounds__(256) void k_merge(const float* __restrict__ pd,
                                               const int* __restrict__ pi,
                                               float4* __restrict__ wi4,
                                               int4* __restrict__ gi4) {
    int b = blockIdx.y;
    int n = blockIdx.x * 256 + threadIdx.x;

    float d0 = 3.4e38f, d1 = 3.4e38f, d2 = 3.4e38f;
    int i0 = 0, i1 = 0, i2 = 0;
#pragma unroll
    for (int ch = 0; ch < SC; ++ch) {
        size_t cb = (size_t)(ch * BB + b) * 3;
#pragma unroll
        for (int j = 0; j < 3; ++j) {
            float d = pd[(cb + j) * NN + n];
            int   s = pi[(cb + j) * NN + n];
            bool c0 = d < d0, c1 = d < d1, c2 = d < d2;
            d2 = __builtin_amdgcn_fmed3f(d1, d, d2);
            d1 = __builtin_amdgcn_fmed3f(d0, d, d1);
            d0 = fminf(d0, d);
            i2 = c1 ? i1 : (c2 ? s : i2);
            i1 = c0 ? i0 : (c1 ? s : i1);
            i0 = c0 ? s : i0;
        }
    }

    float r0 = 1.0f / (d0 + 1e-8f);
    float r1 = 1.0f / (d1 + 1e-8f);
    float r2 = 1.0f / (d2 + 1e-8f);
    float inv = 1.0f / (r0 + r1 + r2);
    size_t q = (size_t)b * NN + n;
    wi4[q] = make_float4(r0 * inv, r1 * inv, r2 * inv, 0.f);
    gi4[q] = make_int4(i0, i1, i2, 0);
}

// ---------------------------------------------------------------------------
// Output: flat grid 4096 blocks, XCD-swizzled: batch = (bid&7)>>1 so each
// XCD's L2 (4 MiB) serves ONE batch's Gh (2.1 MB) -> gathers hit L2 instead
// of thrashing all 4 batches (8.4 MB) across every XCD. Inner structure
// identical to round 9 (64 q x 64 ch per block, 4-query/wave MLP gather).
// Swizzle is a locality heuristic only — correctness is per-block.
// ---------------------------------------------------------------------------
__global__ __launch_bounds__(256) void k_out(const unsigned short* __restrict__ Gh,
                                             const float4* __restrict__ wi4,
                                             const int4* __restrict__ gi4,
                                             float* __restrict__ out) {
    __shared__ float  tile[64 * 68];   // 17.4 KB
    __shared__ float4 swv[64];
    __shared__ int4   siv[64];
    int bid  = blockIdx.x;
    int x    = bid & 7;                // XCD slot (blockIdx % 8 round-robin)
    int b    = x >> 1;                 // 2 XCDs per batch
    int local = (bid >> 3) + (x & 1) * 512;   // 0..1023 per batch
    int nb   = local & 255;            // 256 n-blocks
    int oc   = local >> 8;             // 4 o-chunks
    int n0   = nb * 64;
    int o0   = oc * 64;
    int t    = threadIdx.x;
    int wave = t >> 6;
    int lane = t & 63;
    int qg   = lane >> 4;     // query-in-group 0..3
    int c16  = lane & 15;     // channel quad 0..15

    if (t < 64) {
        size_t q = (size_t)b * NN + n0 + t;
        swv[t] = wi4[q];
        siv[t] = gi4[q];
    }
    __syncthreads();

    const unsigned short* Gb = Gh + (size_t)b * SS * COUT;

#pragma unroll
    for (int pass = 0; pass < 4; ++pass) {
        int q = pass * 16 + wave * 4 + qg;
        float4 wv = swv[q];
        int4   iv = siv[q];
        int co = o0 + c16 * 4;
        ushort4 a0 = *(const ushort4*)(Gb + (size_t)iv.x * COUT + co);
        ushort4 a1 = *(const ushort4*)(Gb + (size_t)iv.y * COUT + co);
        ushort4 a2 = *(const ushort4*)(Gb + (size_t)iv.z * COUT + co);
        float4 v;
        v.x = fmaf(wv.x, bf2f(a0.x), fmaf(wv.y, bf2f(a1.x), wv.z * bf2f(a2.x)));
        v.y = fmaf(wv.x, bf2f(a0.y), fmaf(wv.y, bf2f(a1.y), wv.z * bf2f(a2.y)));
        v.z = fmaf(wv.x, bf2f(a0.z), fmaf(wv.y, bf2f(a1.z), wv.z * bf2f(a2.z)));
        v.w = fmaf(wv.x, bf2f(a0.w), fmaf(wv.y, bf2f(a1.w), wv.z * bf2f(a2.w)));
        *(float4*)&tile[q * 68 + c16 * 4] = v;
    }
    __syncthreads();

    float* obase = out + ((size_t)b * COUT + o0) * NN + n0 + lane;
#pragma unroll
    for (int g = 0; g < 4; ++g) {
        int c = wave * 16 + g * 4;
        float4 v = *(const float4*)&tile[lane * 68 + c];
        obase[(size_t)(c + 0) * NN] = v.x;
        obase[(size_t)(c + 1) * NN] = v.y;
        obase[(size_t)(c + 2) * NN] = v.z;
        obase[(size_t)(c + 3) * NN] = v.w;
    }
}

// ---------------------------------------------------------------------------
extern "C" void kernel_launch(void* const* d_in, const int* in_sizes, int n_in,
                              void* d_out, int out_size, void* d_ws, size_t ws_size,
                              hipStream_t stream) {
    const float* xyz1    = (const float*)d_in[0];   // [B,3,N]
    const float* xyz2    = (const float*)d_in[1];   // [B,3,S]
    const float* points2 = (const float*)d_in[2];   // [B,CIN,S]
    const float* W       = (const float*)d_in[3];   // [COUT,CIN]
    const float* bias    = (const float*)d_in[4];   // [COUT]
    float* out = (float*)d_out;                     // [B,COUT,N]

    char* ws = (char*)d_ws;
    // workspace layout (bytes), total ~23 MB:
    //   pd  : 0        .. 6,291,456   ([SC][B][3][N] f32)
    //   pi  : 6291456  .. 12,582,912  ([SC][B][3][N] i32)
    //   Gh  : 12582912 .. 20,971,520  ([B][S][COUT] bf16)
    //   wi4 : 20971520 .. 22,020,096  ([B][N] float4)
    //   gi4 : 22020096 .. 23,068,672  ([B][N] int4)
    float*          pd  = (float*)(ws);
    int*            pi  = (int*)(ws + 6291456);
    unsigned short* Gh  = (unsigned short*)(ws + 12582912);
    float4*         wi4 = (float4*)(ws + 20971520);
    int4*           gi4 = (int4*)(ws + 22020096);

    k_fused<<<dim3(KNNB + GEMMB), 256, 0, stream>>>(xyz1, xyz2, points2, W, bias,
                                                    Gh, pd, pi);
    k_merge<<<dim3(NN / 256, BB), 256, 0, stream>>>(pd, pi, wi4, gi4);
    k_out<<<dim3(4096), 256, 0, stream>>>(Gh, wi4, gi4, out);
}

// Round 11
// 214.677 us; speedup vs baseline: 1.3248x; 1.0283x over previous
//
#include <hip/hip_runtime.h>

#define BB 4
#define NN 16384
#define SS 4096
#define CIN 256
#define COUT 256

#define SC 8                  // s-chunks for knn
#define SCS (SS / SC)         // 512 points per chunk
#define KNNB ((NN / 512) * SC * BB)           // 32*8*4 = 1024 knn blocks (NPT=2)
#define GEMMB ((COUT / 64) * (SS / 64) * BB)  // 4*64*4 = 1024 gemm blocks

__device__ __forceinline__ unsigned short f2bf(float f) {   // RNE float->bf16
    unsigned u = __float_as_uint(f);
    u += 0x7FFF + ((u >> 16) & 1);
    return (unsigned short)(u >> 16);
}
__device__ __forceinline__ float bf2f(unsigned short h) {
    return __uint_as_float((unsigned)h << 16);
}

// Packed key: kd = (double)e + 640.0 lies in binade [512,1024) (e in (-78,78)),
// so ulp = 2^-43 fixed; low 12 mantissa bits replaced by s => e quantized at
// 2^-31 absolute (flip prob ~1e-4 total) and ordering == (e, s) lexicographic
// == reference stable top_k tie-break. Insert = select-free min/max network.
__device__ __forceinline__ double pack_key(float e, unsigned gs) {
    double kd = (double)e + 640.0;
    unsigned long long b = __double_as_longlong(kd);
    b = (b & 0xFFFFFFFFFFFFF000ULL) | (unsigned long long)gs;
    return __longlong_as_double((long long)b);
}
__device__ __forceinline__ void insert_key(double& k0, double& k1, double& k2,
                                           double x) {
    double m  = fmax(k0, x);
    k0 = fmin(k0, x);
    double m2 = fmax(k1, m);
    k1 = fmin(k1, m);
    k2 = fmin(k2, m2);
}

// ---------------------------------------------------------------------------
// Fused kernel: blocks [0,KNNB) = partial 3-NN; [KNNB,..) = GEMM.
// knn inner loop: 3 fma + cvt/add + and/or + 5 f64 min/max per pair —
// no cmp, no cndmask, no index registers (the R3-R10 2x bloat source).
// ---------------------------------------------------------------------------
__global__ __launch_bounds__(256) void k_fused(const float* __restrict__ xyz1,
                                               const float* __restrict__ xyz2,
                                               const float* __restrict__ P,
                                               const float* __restrict__ W,
                                               const float* __restrict__ bias,
                                               unsigned short* __restrict__ Gh,
                                               unsigned long long* __restrict__ pk) {
    __shared__ float smem[2112];   // 8.25 KB: knn 512 float4; gemm sP+sW
    int bid = blockIdx.x;
    int t   = threadIdx.x;

    if (bid < KNNB) {
        // ---------------- knn path (NPT=2) ----------------
        int nb = bid & 31;
        int ch = (bid >> 5) & 7;
        int b  = bid >> 8;
        int s0 = ch * SCS;

        float4* smv = (float4*)smem;
        const float* x2 = xyz2 + (size_t)b * 3 * SS;
        for (int i = t; i < SCS; i += 256) {
            float px = x2[s0 + i];
            float py = x2[SS + s0 + i];
            float pz = x2[2 * SS + s0 + i];
            smv[i] = make_float4(px, py, pz, fmaf(px, px, fmaf(py, py, pz * pz)));
        }
        __syncthreads();

        int n0  = nb * 512 + t;
        int n1q = n0 + 256;
        const float* xb = xyz1 + (size_t)b * 3 * NN;
        float ax = xb[n0],  ay = xb[NN + n0],  az = xb[2 * NN + n0];
        float bx = xb[n1q], by = xb[NN + n1q], bz = xb[2 * NN + n1q];
        float axm2 = -2.0f * ax, aym2 = -2.0f * ay, azm2 = -2.0f * az;
        float bxm2 = -2.0f * bx, bym2 = -2.0f * by, bzm2 = -2.0f * bz;

        double AK0 = 1023.0, AK1 = 1023.0, AK2 = 1023.0;
        double BK0 = 1023.0, BK1 = 1023.0, BK2 = 1023.0;

#pragma unroll 8
        for (int s = 0; s < SCS; ++s) {
            float4 p = smv[s];
            unsigned gs = (unsigned)(s0 + s);
            {   // e = -2*dot + |p2|^2 ; ranking invariant to +|p1|^2 shift
                float e = fmaf(p.x, axm2, fmaf(p.y, aym2, fmaf(p.z, azm2, p.w)));
                insert_key(AK0, AK1, AK2, pack_key(e, gs));
            }
            {
                float e = fmaf(p.x, bxm2, fmaf(p.y, bym2, fmaf(p.z, bzm2, p.w)));
                insert_key(BK0, BK1, BK2, pack_key(e, gs));
            }
        }

        // layout [ch][b][j][n], u64 keys (coalesced 8B/lane)
        size_t cb = (size_t)(ch * BB + b) * 3;
        pk[(cb + 0) * NN + n0]  = (unsigned long long)__double_as_longlong(AK0);
        pk[(cb + 1) * NN + n0]  = (unsigned long long)__double_as_longlong(AK1);
        pk[(cb + 2) * NN + n0]  = (unsigned long long)__double_as_longlong(AK2);
        pk[(cb + 0) * NN + n1q] = (unsigned long long)__double_as_longlong(BK0);
        pk[(cb + 1) * NN + n1q] = (unsigned long long)__double_as_longlong(BK1);
        pk[(cb + 2) * NN + n1q] = (unsigned long long)__double_as_longlong(BK2);
    } else {
        // ---------------- gemm path: 64s x 64o tile, 4x4 micro ----------
        int g  = bid - KNNB;
        int o0 = (g & 3) * 64;
        int s0 = ((g >> 2) & 63) * 64;
        int b  = g >> 8;
        float* sP = smem;              // 16 x 64
        float* sW = smem + 1024;       // 16 x 68 (padded)
        int i = t & 15;
        int j = t >> 4;

        float acc[4][4];
#pragma unroll
        for (int p = 0; p < 4; ++p)
#pragma unroll
            for (int q = 0; q < 4; ++q) acc[p][q] = 0.f;

        const float* Pb = P + (size_t)b * CIN * SS;

        for (int c0 = 0; c0 < CIN; c0 += 16) {
            __syncthreads();
            {
                int col = t & 63;
                int r0r = t >> 6;
#pragma unroll
                for (int r = 0; r < 4; ++r) {
                    int row = r0r + r * 4;
                    sP[row * 64 + col] = Pb[(size_t)(c0 + row) * SS + s0 + col];
                }
            }
            {
                int cc = t & 15;
                int obase = t >> 4;
#pragma unroll
                for (int r = 0; r < 4; ++r) {
                    int oo = obase + 16 * r;
                    sW[cc * 68 + oo] = W[(size_t)(o0 + oo) * CIN + c0 + cc];
                }
            }
            __syncthreads();

#pragma unroll
            for (int cc = 0; cc < 16; ++cc) {
                float4 a  = *(const float4*)&sP[cc * 64 + i * 4];
                float4 bv = *(const float4*)&sW[cc * 68 + j * 4];
                float av[4] = {a.x, a.y, a.z, a.w};
                float bw[4] = {bv.x, bv.y, bv.z, bv.w};
#pragma unroll
                for (int p = 0; p < 4; ++p)
#pragma unroll
                    for (int q = 0; q < 4; ++q)
                        acc[p][q] = fmaf(av[p], bw[q], acc[p][q]);
            }
        }

        float b0 = bias[o0 + j * 4 + 0];
        float b1 = bias[o0 + j * 4 + 1];
        float b2 = bias[o0 + j * 4 + 2];
        float b3 = bias[o0 + j * 4 + 3];
#pragma unroll
        for (int p = 0; p < 4; ++p) {
            ushort4 v;
            v.x = f2bf(acc[p][0] + b0);
            v.y = f2bf(acc[p][1] + b1);
            v.z = f2bf(acc[p][2] + b2);
            v.w = f2bf(acc[p][3] + b3);
            size_t off = ((size_t)b * SS + s0 + i * 4 + p) * COUT + o0 + j * 4;
            *(ushort4*)&Gh[off] = v;
        }
    }
}

// ---------------------------------------------------------------------------
// Merge: fold 24 packed keys per query via the same select-free network
// (order-independent: keys are globally ordered incl. index tie-break),
// recompute |p1|^2 from xyz1, decode {d, s}, weights -> wi4/gi4.
// ---------------------------------------------------------------------------
__global__ __launch_bounds__(256) void k_merge(const unsigned long long* __restrict__ pk,
                                               const float* __restrict__ xyz1,
                                               float4* __restrict__ wi4,
                                               int4* __restrict__ gi4) {
    int b = blockIdx.y;
    int n = blockIdx.x * 256 + threadIdx.x;

    double k0 = 1023.0, k1 = 1023.0, k2 = 1023.0;
#pragma unroll
    for (int ch = 0; ch < SC; ++ch) {
        size_t cb = (size_t)(ch * BB + b) * 3;
#pragma unroll
        for (int j = 0; j < 3; ++j) {
            double x = __longlong_as_double(
                (long long)pk[(cb + j) * NN + n]);
            insert_key(k0, k1, k2, x);
        }
    }

    const float* xb = xyz1 + (size_t)b * 3 * NN;
    float qx = xb[n], qy = xb[NN + n], qz = xb[2 * NN + n];
    float n1 = fmaf(qx, qx, fmaf(qy, qy, qz * qz));

    unsigned long long u0 = (unsigned long long)__double_as_longlong(k0);
    unsigned long long u1 = (unsigned long long)__double_as_longlong(k1);
    unsigned long long u2 = (unsigned long long)__double_as_longlong(k2);
    float e0 = (float)(__longlong_as_double((long long)(u0 & ~0xFFFULL)) - 640.0);
    float e1 = (float)(__longlong_as_double((long long)(u1 & ~0xFFFULL)) - 640.0);
    float e2 = (float)(__longlong_as_double((long long)(u2 & ~0xFFFULL)) - 640.0);
    float d0 = e0 + n1, d1 = e1 + n1, d2 = e2 + n1;

    float r0 = 1.0f / (d0 + 1e-8f);
    float r1 = 1.0f / (d1 + 1e-8f);
    float r2 = 1.0f / (d2 + 1e-8f);
    float inv = 1.0f / (r0 + r1 + r2);
    size_t q = (size_t)b * NN + n;
    wi4[q] = make_float4(r0 * inv, r1 * inv, r2 * inv, 0.f);
    gi4[q] = make_int4((int)(u0 & 0xFFFULL), (int)(u1 & 0xFFFULL),
                       (int)(u2 & 0xFFFULL), 0);
}

// ---------------------------------------------------------------------------
// Output: unchanged from round 10 (XCD-swizzled flat grid, 64q x 64ch blocks,
// 4-query/wave MLP gather, stride-68 tile, coalesced stores).
// ---------------------------------------------------------------------------
__global__ __launch_bounds__(256) void k_out(const unsigned short* __restrict__ Gh,
                                             const float4* __restrict__ wi4,
                                             const int4* __restrict__ gi4,
                                             float* __restrict__ out) {
    __shared__ float  tile[64 * 68];   // 17.4 KB
    __shared__ float4 swv[64];
    __shared__ int4   siv[64];
    int bid  = blockIdx.x;
    int x    = bid & 7;                // XCD slot (blockIdx % 8 round-robin)
    int b    = x >> 1;                 // 2 XCDs per batch
    int local = (bid >> 3) + (x & 1) * 512;   // 0..1023 per batch
    int nb   = local & 255;            // 256 n-blocks
    int oc   = local >> 8;             // 4 o-chunks
    int n0   = nb * 64;
    int o0   = oc * 64;
    int t    = threadIdx.x;
    int wave = t >> 6;
    int lane = t & 63;
    int qg   = lane >> 4;     // query-in-group 0..3
    int c16  = lane & 15;     // channel quad 0..15

    if (t < 64) {
        size_t q = (size_t)b * NN + n0 + t;
        swv[t] = wi4[q];
        siv[t] = gi4[q];
    }
    __syncthreads();

    const unsigned short* Gb = Gh + (size_t)b * SS * COUT;

#pragma unroll
    for (int pass = 0; pass < 4; ++pass) {
        int q = pass * 16 + wave * 4 + qg;
        float4 wv = swv[q];
        int4   iv = siv[q];
        int co = o0 + c16 * 4;
        ushort4 a0 = *(const ushort4*)(Gb + (size_t)iv.x * COUT + co);
        ushort4 a1 = *(const ushort4*)(Gb + (size_t)iv.y * COUT + co);
        ushort4 a2 = *(const ushort4*)(Gb + (size_t)iv.z * COUT + co);
        float4 v;
        v.x = fmaf(wv.x, bf2f(a0.x), fmaf(wv.y, bf2f(a1.x), wv.z * bf2f(a2.x)));
        v.y = fmaf(wv.x, bf2f(a0.y), fmaf(wv.y, bf2f(a1.y), wv.z * bf2f(a2.y)));
        v.z = fmaf(wv.x, bf2f(a0.z), fmaf(wv.y, bf2f(a1.z), wv.z * bf2f(a2.z)));
        v.w = fmaf(wv.x, bf2f(a0.w), fmaf(wv.y, bf2f(a1.w), wv.z * bf2f(a2.w)));
        *(float4*)&tile[q * 68 + c16 * 4] = v;
    }
    __syncthreads();

    float* obase = out + ((size_t)b * COUT + o0) * NN + n0 + lane;
#pragma unroll
    for (int g = 0; g < 4; ++g) {
        int c = wave * 16 + g * 4;
        float4 v = *(const float4*)&tile[lane * 68 + c];
        obase[(size_t)(c + 0) * NN] = v.x;
        obase[(size_t)(c + 1) * NN] = v.y;
        obase[(size_t)(c + 2) * NN] = v.z;
        obase[(size_t)(c + 3) * NN] = v.w;
    }
}

// ---------------------------------------------------------------------------
extern "C" void kernel_launch(void* const* d_in, const int* in_sizes, int n_in,
                              void* d_out, int out_size, void* d_ws, size_t ws_size,
                              hipStream_t stream) {
    const float* xyz1    = (const float*)d_in[0];   // [B,3,N]
    const float* xyz2    = (const float*)d_in[1];   // [B,3,S]
    const float* points2 = (const float*)d_in[2];   // [B,CIN,S]
    const float* W       = (const float*)d_in[3];   // [COUT,CIN]
    const float* bias    = (const float*)d_in[4];   // [COUT]
    float* out = (float*)d_out;                     // [B,COUT,N]

    char* ws = (char*)d_ws;
    // workspace layout (bytes), total ~23 MB:
    //   pk  : 0        .. 12,582,912  ([SC][B][3][N] u64 packed keys)
    //   Gh  : 12582912 .. 20,971,520  ([B][S][COUT] bf16)
    //   wi4 : 20971520 .. 22,020,096  ([B][N] float4)
    //   gi4 : 22020096 .. 23,068,672  ([B][N] int4)
    unsigned long long* pk  = (unsigned long long*)(ws);
    unsigned short*     Gh  = (unsigned short*)(ws + 12582912);
    float4*             wi4 = (float4*)(ws + 20971520);
    int4*               gi4 = (int4*)(ws + 22020096);

    k_fused<<<dim3(KNNB + GEMMB), 256, 0, stream>>>(xyz1, xyz2, points2, W, bias,
                                                    Gh, pk);
    k_merge<<<dim3(NN / 256, BB), 256, 0, stream>>>(pk, xyz1, wi4, gi4);
    k_out<<<dim3(4096), 256, 0, stream>>>(Gh, wi4, gi4, out);
}